// Round 2
// baseline (3820.435 us; speedup 1.0000x reference)
//
#include <hip/hip_runtime.h>
#include <math.h>

#define NPIX 9216   // 96*96
#define BATCH 8
#define HEADS 8
#define HD 32
#define RR 64

// ---------- GEMM: Y[b,o,n] = bias[o] + sum_c W[o,c] * X[b,c,n] ----------
__global__ __launch_bounds__(256) void gemm_conv(
    const float* __restrict__ W, const float* __restrict__ bias,
    const float* __restrict__ X, float* __restrict__ Y,
    int O, int C, int N) {
  __shared__ float Ws[64][17];
  __shared__ float Xs[16][65];
  int b = blockIdx.z;
  const float* Xb = X + (size_t)b * C * N;
  float* Yb = Y + (size_t)b * O * N;
  int n0 = blockIdx.x * 64;
  int o0 = blockIdx.y * 64;
  int t = threadIdx.x;
  int tx = t & 15, ty = t >> 4;
  float acc[4][4] = {};
  for (int k0 = 0; k0 < C; k0 += 16) {
    for (int i = t; i < 64 * 16; i += 256) {
      int row = i >> 4, col = i & 15;
      Ws[row][col] = W[(size_t)(o0 + row) * C + k0 + col];
    }
    for (int i = t; i < 16 * 64; i += 256) {
      int row = i >> 6, col = i & 63;
      Xs[row][col] = Xb[(size_t)(k0 + row) * N + n0 + col];
    }
    __syncthreads();
#pragma unroll
    for (int k = 0; k < 16; ++k) {
      float xv[4], wv[4];
#pragma unroll
      for (int j = 0; j < 4; ++j) xv[j] = Xs[k][tx * 4 + j];
#pragma unroll
      for (int i = 0; i < 4; ++i) wv[i] = Ws[ty * 4 + i][k];
#pragma unroll
      for (int i = 0; i < 4; ++i)
#pragma unroll
        for (int j = 0; j < 4; ++j) acc[i][j] += wv[i] * xv[j];
    }
    __syncthreads();
  }
#pragma unroll
  for (int i = 0; i < 4; ++i) {
    int o = o0 + ty * 4 + i;
    float bv = bias[o];
#pragma unroll
    for (int j = 0; j < 4; ++j)
      Yb[(size_t)o * N + n0 + tx * 4 + j] = acc[i][j] + bv;
  }
}

// ---------- Softmax over 512 channels, in place. A: (B, 512, N) ----------
__global__ __launch_bounds__(256) void softmax_ch(float* __restrict__ A, int N) {
  const int Cch = 512;
  int b = blockIdx.y;
  int n = blockIdx.x * 256 + threadIdx.x;
  float* Ab = A + (size_t)b * Cch * N + n;
  float m = -1e30f;
  for (int c = 0; c < Cch; ++c) m = fmaxf(m, Ab[(size_t)c * N]);
  float s = 0.f;
  for (int c = 0; c < Cch; ++c) s += expf(Ab[(size_t)c * N] - m);
  float inv = 1.f / s;
  for (int c = 0; c < Cch; ++c) {
    Ab[(size_t)c * N] = expf(Ab[(size_t)c * N] - m) * inv;
  }
}

// ---------- Row sums: S[b,r] = sum_n A[b,r,n], A: (B,512,N) ----------
__global__ __launch_bounds__(256) void rowsum(
    const float* __restrict__ A, float* __restrict__ S, int N) {
  int b = blockIdx.y;
  int row = blockIdx.x * 4 + (threadIdx.x >> 6);
  int lane = threadIdx.x & 63;
  const float* p = A + ((size_t)b * 512 + row) * N;
  float s = 0.f;
  for (int n = lane; n < N; n += 64) s += p[n];
#pragma unroll
  for (int off = 32; off > 0; off >>= 1) s += __shfl_down(s, off, 64);
  if (lane == 0) S[(size_t)b * 512 + row] = s;
}

// ---------- Cross product: T[b,c,r] = sum_n X[b,c,n] * Rm[b,r,n] ----------
// X: (B,256,N), Rm: (B,512,N), T: (B,256,512). Tile 64(c) x 64(r), full K.
__global__ __launch_bounds__(256) void gemm_T(
    const float* __restrict__ X, const float* __restrict__ Rm,
    float* __restrict__ T, int N) {
  __shared__ float Xs[64][65];
  __shared__ float Rs[64][65];
  int b = blockIdx.z;
  int r0 = blockIdx.x * 64;
  int c0 = blockIdx.y * 64;
  const float* Xb = X + ((size_t)b * 256 + c0) * N;
  const float* Rb = Rm + ((size_t)b * 512 + r0) * N;
  int t = threadIdx.x;
  int tx = t & 15, ty = t >> 4;
  float acc[4][4] = {};
  for (int n0 = 0; n0 < N; n0 += 64) {
    for (int i = t; i < 64 * 64; i += 256) {
      int row = i >> 6, col = i & 63;
      Xs[row][col] = Xb[(size_t)row * N + n0 + col];
      Rs[row][col] = Rb[(size_t)row * N + n0 + col];
    }
    __syncthreads();
#pragma unroll 4
    for (int n = 0; n < 64; ++n) {
      float cv[4], rv[4];
#pragma unroll
      for (int i = 0; i < 4; ++i) cv[i] = Xs[ty * 4 + i][n];
#pragma unroll
      for (int j = 0; j < 4; ++j) rv[j] = Rs[tx * 4 + j][n];
#pragma unroll
      for (int i = 0; i < 4; ++i)
#pragma unroll
        for (int j = 0; j < 4; ++j) acc[i][j] += cv[i] * rv[j];
    }
    __syncthreads();
  }
#pragma unroll
  for (int i = 0; i < 4; ++i)
#pragma unroll
    for (int j = 0; j < 4; ++j)
      T[((size_t)b * 256 + c0 + ty * 4 + i) * 512 + r0 + tx * 4 + j] = acc[i][j];
}

// ---------- Fold projections into region space ----------
// qr[b,h,d,r] = sum_c Wq[h*32+d,c]*T1[b,c,h*64+r] + bq[h*32+d]*S1[b,h*64+r]
// kr: Wkv row h*64+d;  vr: Wkv row h*64+32+d  (with T2, S2)
__global__ __launch_bounds__(256) void fold_qkv(
    const float* __restrict__ T1, const float* __restrict__ T2,
    const float* __restrict__ S1, const float* __restrict__ S2,
    const float* __restrict__ Wq, const float* __restrict__ bq,
    const float* __restrict__ Wkv, const float* __restrict__ bkv,
    float* __restrict__ qr, float* __restrict__ kr, float* __restrict__ vr) {
  int h = blockIdx.x, b = blockIdx.y;
  int t = threadIdx.x;
  int r = t & 63, d0 = (t >> 6) * 8;
  const float* T1b = T1 + (size_t)b * 256 * 512 + h * 64 + r;
  const float* T2b = T2 + (size_t)b * 256 * 512 + h * 64 + r;
  float aq[8] = {}, ak[8] = {}, av[8] = {};
  for (int c = 0; c < 256; ++c) {
    float t1 = T1b[(size_t)c * 512];
    float t2 = T2b[(size_t)c * 512];
#pragma unroll
    for (int i = 0; i < 8; ++i) {
      int d = d0 + i;
      aq[i] += Wq[(size_t)(h * 32 + d) * 256 + c] * t1;
      ak[i] += Wkv[(size_t)(h * 64 + d) * 256 + c] * t2;
      av[i] += Wkv[(size_t)(h * 64 + 32 + d) * 256 + c] * t2;
    }
  }
  float s1 = S1[(size_t)b * 512 + h * 64 + r];
  float s2 = S2[(size_t)b * 512 + h * 64 + r];
  size_t off = ((size_t)b * HEADS + h) * 32 * 64;
#pragma unroll
  for (int i = 0; i < 8; ++i) {
    int d = d0 + i;
    if (d < 32) qr[off + (size_t)d * 64 + r] = aq[i] + bq[h * 32 + d] * s1;
    kr[off + (size_t)(d % 32) * 64 + r] = 0.f;  // placeholder overwritten below
  }
  // write kr/vr for d in [0,32): threads with d0 in {0,8,16,24} all have d<32? d0+7<=31 yes.
#pragma unroll
  for (int i = 0; i < 8; ++i) {
    int d = d0 + i;
    kr[off + (size_t)d * 64 + r] = ak[i] + bkv[h * 64 + d] * s2;
    vr[off + (size_t)d * 64 + r] = av[i] + bkv[h * 64 + 32 + d] * s2;
  }
}

// ---------- Region attention + Wout fold. One block per (b,h). ----------
__global__ __launch_bounds__(256) void region_attn(
    const float* __restrict__ qr, const float* __restrict__ kr,
    const float* __restrict__ vr, const float* __restrict__ Wout,
    float* __restrict__ M) {
  int h = blockIdx.x, b = blockIdx.y;
  __shared__ float qrs[32 * 64];
  __shared__ float krs[32 * 64];
  __shared__ float vrs[32 * 64];
  __shared__ float sc[64][65];
  __shared__ float vals[32][64];
  size_t off = ((size_t)b * HEADS + h) * 32 * 64;
  int t = threadIdx.x;
  for (int i = t; i < 2048; i += 256) {
    qrs[i] = qr[off + i];
    krs[i] = kr[off + i];
    vrs[i] = vr[off + i];
  }
  __syncthreads();
  for (int idx = t; idx < 4096; idx += 256) {
    int qq = idx >> 6, kk = idx & 63;
    float s = 0.f;
#pragma unroll
    for (int d = 0; d < 32; ++d) s += qrs[d * 64 + qq] * krs[d * 64 + kk];
    sc[qq][kk] = s * 0.17677669529663687f;
  }
  __syncthreads();
  if (t < 64) {
    float m = -1e30f;
    for (int k = 0; k < 64; ++k) m = fmaxf(m, sc[t][k]);
    float s = 0.f;
    for (int k = 0; k < 64; ++k) { float e = expf(sc[t][k] - m); sc[t][k] = e; s += e; }
    float inv = 1.f / s;
    for (int k = 0; k < 64; ++k) sc[t][k] *= inv;
  }
  __syncthreads();
  for (int idx = t; idx < 2048; idx += 256) {
    int d = idx >> 6, qq = idx & 63;
    float s = 0.f;
#pragma unroll
    for (int k = 0; k < 64; ++k) s += vrs[d * 64 + k] * sc[qq][k];
    vals[d][qq] = s;
  }
  __syncthreads();
  int o = t;
  float w[32];
#pragma unroll
  for (int d = 0; d < 32; ++d) w[d] = Wout[(size_t)o * 256 + h * 32 + d];
  float* Mp = M + ((size_t)b * 256 + o) * 512 + h * 64;
  for (int r = 0; r < 64; ++r) {
    float s = 0.f;
#pragma unroll
    for (int d = 0; d < 32; ++d) s += w[d] * vals[d][r];
    Mp[r] = s;
  }
}

// ---------- Final: Y = tgt + alpha*(M @ Rq + bout) ----------
__global__ __launch_bounds__(256) void gemm_final(
    const float* __restrict__ M, const float* __restrict__ bout,
    const float* __restrict__ Rq, const float* __restrict__ tgt,
    const float* __restrict__ alpha_p, float* __restrict__ Y, int N) {
  const int O = 256, C = 512;
  __shared__ float Ws[64][17];
  __shared__ float Xs[16][65];
  int b = blockIdx.z;
  const float* Wb = M + (size_t)b * O * C;
  const float* Xb = Rq + (size_t)b * C * N;
  const float* Tb = tgt + (size_t)b * O * N;
  float* Yb = Y + (size_t)b * O * N;
  float alpha = alpha_p[0];
  int n0 = blockIdx.x * 64;
  int o0 = blockIdx.y * 64;
  int t = threadIdx.x;
  int tx = t & 15, ty = t >> 4;
  float acc[4][4] = {};
  for (int k0 = 0; k0 < C; k0 += 16) {
    for (int i = t; i < 64 * 16; i += 256) {
      int row = i >> 4, col = i & 15;
      Ws[row][col] = Wb[(size_t)(o0 + row) * C + k0 + col];
    }
    for (int i = t; i < 16 * 64; i += 256) {
      int row = i >> 6, col = i & 63;
      Xs[row][col] = Xb[(size_t)(k0 + row) * N + n0 + col];
    }
    __syncthreads();
#pragma unroll
    for (int k = 0; k < 16; ++k) {
      float xv[4], wv[4];
#pragma unroll
      for (int j = 0; j < 4; ++j) xv[j] = Xs[k][tx * 4 + j];
#pragma unroll
      for (int i = 0; i < 4; ++i) wv[i] = Ws[ty * 4 + i][k];
#pragma unroll
      for (int i = 0; i < 4; ++i)
#pragma unroll
        for (int j = 0; j < 4; ++j) acc[i][j] += wv[i] * xv[j];
    }
    __syncthreads();
  }
#pragma unroll
  for (int i = 0; i < 4; ++i) {
    int o = o0 + ty * 4 + i;
    float bv = bout[o];
#pragma unroll
    for (int j = 0; j < 4; ++j) {
      size_t idx = (size_t)o * N + n0 + tx * 4 + j;
      Yb[idx] = Tb[idx] + alpha * (acc[i][j] + bv);
    }
  }
}

extern "C" void kernel_launch(void* const* d_in, const int* in_sizes, int n_in,
                              void* d_out, int out_size, void* d_ws, size_t ws_size,
                              hipStream_t stream) {
  const float* src  = (const float*)d_in[0];
  const float* tgt  = (const float*)d_in[1];
  const float* Wq   = (const float*)d_in[2];
  const float* bq   = (const float*)d_in[3];
  const float* Wkv  = (const float*)d_in[4];
  const float* bkv  = (const float*)d_in[5];
  const float* Wrq  = (const float*)d_in[6];
  const float* brq  = (const float*)d_in[7];
  const float* Wrk  = (const float*)d_in[8];
  const float* brk  = (const float*)d_in[9];
  const float* Wout = (const float*)d_in[10];
  const float* bout = (const float*)d_in[11];
  const float* alpha = (const float*)d_in[12];
  float* out = (float*)d_out;

  const int N = NPIX;
  float* ws = (float*)d_ws;
  float* big = ws;                                  // 8*512*9216 = 37.75M floats
  float* T1  = big + (size_t)BATCH * 512 * N;       // 8*256*512
  float* T2  = T1 + (size_t)BATCH * 256 * 512;
  float* S1  = T2 + (size_t)BATCH * 256 * 512;      // 8*512
  float* S2  = S1 + (size_t)BATCH * 512;
  float* qr  = S2 + (size_t)BATCH * 512;            // 8*8*32*64 each
  float* kr  = qr + (size_t)BATCH * HEADS * 32 * 64;
  float* vr  = kr + (size_t)BATCH * HEADS * 32 * 64;
  float* M   = vr + (size_t)BATCH * HEADS * 32 * 64;  // 8*256*512

  dim3 blk(256);
  // --- Rk phase: big = softmax(Wrk @ src + brk) ---
  gemm_conv<<<dim3(N / 64, 512 / 64, BATCH), blk, 0, stream>>>(Wrk, brk, src, big, 512, 256, N);
  softmax_ch<<<dim3(N / 256, BATCH), blk, 0, stream>>>(big, N);
  rowsum<<<dim3(512 / 4, BATCH), blk, 0, stream>>>(big, S2, N);
  gemm_T<<<dim3(512 / 64, 256 / 64, BATCH), blk, 0, stream>>>(src, big, T2, N);
  // --- Rq phase: big = softmax(Wrq @ tgt + brq)  (persists to the end) ---
  gemm_conv<<<dim3(N / 64, 512 / 64, BATCH), blk, 0, stream>>>(Wrq, brq, tgt, big, 512, 256, N);
  softmax_ch<<<dim3(N / 256, BATCH), blk, 0, stream>>>(big, N);
  rowsum<<<dim3(512 / 4, BATCH), blk, 0, stream>>>(big, S1, N);
  gemm_T<<<dim3(512 / 64, 256 / 64, BATCH), blk, 0, stream>>>(tgt, big, T1, N);
  // --- fold to region space, attention, back-projection ---
  fold_qkv<<<dim3(HEADS, BATCH), blk, 0, stream>>>(T1, T2, S1, S2, Wq, bq, Wkv, bkv, qr, kr, vr);
  region_attn<<<dim3(HEADS, BATCH), blk, 0, stream>>>(qr, kr, vr, Wout, M);
  gemm_final<<<dim3(N / 64, 256 / 64, BATCH), blk, 0, stream>>>(M, bout, big, tgt, alpha, out, N);
}

// Round 3
// 1568.859 us; speedup vs baseline: 2.4352x; 2.4352x over previous
//
#include <hip/hip_runtime.h>
#include <math.h>

#define NPIX 9216   // 96*96
#define BATCH 8
#define HEADS 8

typedef __bf16 bf16;
typedef __bf16 bf16x8 __attribute__((ext_vector_type(8)));
typedef __bf16 bf16x4 __attribute__((ext_vector_type(4)));
typedef float f32x4 __attribute__((ext_vector_type(4)));

__device__ __forceinline__ void load_lds16(const bf16* g, bf16* l) {
  __builtin_amdgcn_global_load_lds(
      (const __attribute__((address_space(1))) void*)g,
      (__attribute__((address_space(3))) void*)l, 16, 0, 0);
}

// ---------- fp32 -> bf16 elementwise ----------
__global__ __launch_bounds__(256) void cvt_f2b(const float* __restrict__ in,
                                               bf16* __restrict__ out, int n) {
  int i = blockIdx.x * 256 + threadIdx.x;
  if (i < n) out[i] = (bf16)in[i];
}

// ---------- transpose+cvt: (B,C,N) fp32 -> (B,N,C) bf16 ----------
__global__ __launch_bounds__(256) void transpose_cvt(
    const float* __restrict__ in, bf16* __restrict__ out, int C, int N) {
  __shared__ float tile[32][33];
  int b = blockIdx.z;
  int n0 = blockIdx.x * 32, c0 = blockIdx.y * 32;
  int tx = threadIdx.x & 31, ty = threadIdx.x >> 5;
#pragma unroll
  for (int k = 0; k < 4; ++k)
    tile[ty + k * 8][tx] = in[((size_t)b * C + c0 + ty + k * 8) * N + n0 + tx];
  __syncthreads();
#pragma unroll
  for (int k = 0; k < 4; ++k)
    out[((size_t)b * N + n0 + ty + k * 8) * C + c0 + tx] = (bf16)tile[tx][ty + k * 8];
}

// ---------- transpose bf16: (B,512,N) -> (B,N,512) ----------
__global__ __launch_bounds__(256) void transpose_bf(
    const bf16* __restrict__ in, bf16* __restrict__ out, int C, int N) {
  __shared__ bf16 tile[32][33];
  int b = blockIdx.z;
  int n0 = blockIdx.x * 32, c0 = blockIdx.y * 32;
  int tx = threadIdx.x & 31, ty = threadIdx.x >> 5;
#pragma unroll
  for (int k = 0; k < 4; ++k)
    tile[ty + k * 8][tx] = in[((size_t)b * C + c0 + ty + k * 8) * N + n0 + tx];
  __syncthreads();
#pragma unroll
  for (int k = 0; k < 4; ++k)
    out[((size_t)b * N + n0 + ty + k * 8) * C + c0 + tx] = tile[tx][ty + k * 8];
}

// ---------- MFMA conv: Y[b,o,n](bf16) = bias[o] + sum_c W[o,c]*Xt[b,n,c] ----------
// W: (O,256) bf16. Xt: (B,N,256) bf16. 128x128 tile, BK=32.
__global__ __launch_bounds__(256) void mfma_conv(
    const bf16* __restrict__ W, const float* __restrict__ bias,
    const bf16* __restrict__ Xt, bf16* __restrict__ Y, int O, int N) {
  const int K = 256;
  __shared__ bf16 As[128 * 32];
  __shared__ bf16 Bs[128 * 32];
  int b = blockIdx.z;
  int n0 = blockIdx.x * 128, o0 = blockIdx.y * 128;
  const bf16* Xb = Xt + (size_t)b * N * K;
  int t = threadIdx.x;
  int lane = t & 63, wave = t >> 6;
  int wr = wave >> 1, wc = wave & 1;
  f32x4 acc[4][4] = {};
  for (int k0 = 0; k0 < K; k0 += 32) {
#pragma unroll
    for (int p = 0; p < 2; ++p) {
      int u = p * 256 + t;
      int ub = p * 256 + (t & 192);
      load_lds16(&W[(size_t)(o0 + (u >> 2)) * K + k0 + (u & 3) * 8], &As[ub * 8]);
      load_lds16(&Xb[(size_t)(n0 + (u >> 2)) * K + k0 + (u & 3) * 8], &Bs[ub * 8]);
    }
    __syncthreads();
    bf16x8 bfrag[4];
#pragma unroll
    for (int j = 0; j < 4; ++j)
      bfrag[j] = *(const bf16x8*)&Bs[(wc * 64 + j * 16 + (lane & 15)) * 32 + (lane >> 4) * 8];
#pragma unroll
    for (int i = 0; i < 4; ++i) {
      bf16x8 a = *(const bf16x8*)&As[(wr * 64 + i * 16 + (lane & 15)) * 32 + (lane >> 4) * 8];
#pragma unroll
      for (int j = 0; j < 4; ++j)
        acc[i][j] = __builtin_amdgcn_mfma_f32_16x16x32_bf16(a, bfrag[j], acc[i][j], 0, 0, 0);
    }
    __syncthreads();
  }
  bf16* Yb = Y + (size_t)b * O * N;
  int quad = lane >> 4, col16 = lane & 15;
#pragma unroll
  for (int i = 0; i < 4; ++i) {
#pragma unroll
    for (int reg = 0; reg < 4; ++reg) {
      int row = o0 + wr * 64 + i * 16 + quad * 4 + reg;
      float bv = bias[row];
#pragma unroll
      for (int j = 0; j < 4; ++j) {
        int col = n0 + wc * 64 + j * 16 + col16;
        Yb[(size_t)row * N + col] = (bf16)(acc[i][j][reg] + bv);
      }
    }
  }
}

// ---------- softmax over 512 channels in place, bf16 ----------
__global__ __launch_bounds__(256) void softmax_bf(bf16* __restrict__ A, int N) {
  int b = blockIdx.y;
  int n = blockIdx.x * 256 + threadIdx.x;
  bf16* Ab = A + (size_t)b * 512 * N + n;
  float m = -1e30f;
  for (int c = 0; c < 512; ++c) m = fmaxf(m, (float)Ab[(size_t)c * N]);
  float s = 0.f;
  for (int c = 0; c < 512; ++c) s += expf((float)Ab[(size_t)c * N] - m);
  float inv = 1.f / s;
  for (int c = 0; c < 512; ++c)
    Ab[(size_t)c * N] = (bf16)(expf((float)Ab[(size_t)c * N] - m) * inv);
}

// ---------- row sums of bf16 Rm: S[b,r] = sum_n Rm[b,r,n] ----------
__global__ __launch_bounds__(256) void rowsum_bf(
    const bf16* __restrict__ A, float* __restrict__ S, int N) {
  int b = blockIdx.y;
  int row = blockIdx.x * 4 + (threadIdx.x >> 6);
  int lane = threadIdx.x & 63;
  const bf16* p = A + ((size_t)b * 512 + row) * N;
  float s = 0.f;
  for (int n = lane; n < N; n += 64) s += (float)p[n];
#pragma unroll
  for (int off = 32; off > 0; off >>= 1) s += __shfl_down(s, off, 64);
  if (lane == 0) S[(size_t)b * 512 + row] = s;
}

// ---------- gemm_T (MFMA, split-K): Tt[b,r,c] += sum_n Rm[b,r,n]*X[b,c,n] ----------
// Rm: (B,512,N) bf16 (A-operand). X: (B,256,N) fp32 (B-operand, cvt in-kernel).
// Tile 128(r) x 128(c), BK=32 over n, split-K=16 via blockIdx.z. atomicAdd fp32.
__global__ __launch_bounds__(256) void gemm_T_mfma(
    const bf16* __restrict__ Rm, const float* __restrict__ Xf,
    float* __restrict__ Tt, int N) {
  __shared__ bf16 As[128 * 32];
  __shared__ bf16 Bs[128 * 32];
  int z = blockIdx.z;
  int b = z >> 4, ks = z & 15;
  int klen = N / 16;
  int kbase = ks * klen;
  int c0 = blockIdx.x * 128, r0 = blockIdx.y * 128;
  const bf16* Rb = Rm + (size_t)b * 512 * N;
  const float* Xb = Xf + (size_t)b * 256 * N;
  int t = threadIdx.x;
  int lane = t & 63, wave = t >> 6;
  int wr = wave >> 1, wc = wave & 1;
  f32x4 acc[4][4] = {};
  for (int kk = kbase; kk < kbase + klen; kk += 32) {
#pragma unroll
    for (int p = 0; p < 2; ++p) {
      int u = p * 256 + t;
      int ub = p * 256 + (t & 192);
      load_lds16(&Rb[(size_t)(r0 + (u >> 2)) * N + kk + (u & 3) * 8], &As[ub * 8]);
    }
#pragma unroll
    for (int p = 0; p < 4; ++p) {
      int u = p * 256 + t;
      int row = u >> 3, c4 = u & 7;
      const float4 v = *(const float4*)&Xb[(size_t)(c0 + row) * N + kk + c4 * 4];
      bf16x4 w = {(bf16)v.x, (bf16)v.y, (bf16)v.z, (bf16)v.w};
      *(bf16x4*)&Bs[row * 32 + c4 * 4] = w;
    }
    __syncthreads();
    bf16x8 bfrag[4];
#pragma unroll
    for (int j = 0; j < 4; ++j)
      bfrag[j] = *(const bf16x8*)&Bs[(wc * 64 + j * 16 + (lane & 15)) * 32 + (lane >> 4) * 8];
#pragma unroll
    for (int i = 0; i < 4; ++i) {
      bf16x8 a = *(const bf16x8*)&As[(wr * 64 + i * 16 + (lane & 15)) * 32 + (lane >> 4) * 8];
#pragma unroll
      for (int j = 0; j < 4; ++j)
        acc[i][j] = __builtin_amdgcn_mfma_f32_16x16x32_bf16(a, bfrag[j], acc[i][j], 0, 0, 0);
    }
    __syncthreads();
  }
  int quad = lane >> 4, col16 = lane & 15;
  float* Tb = Tt + (size_t)b * 512 * 256;
#pragma unroll
  for (int i = 0; i < 4; ++i) {
#pragma unroll
    for (int reg = 0; reg < 4; ++reg) {
      int r = r0 + wr * 64 + i * 16 + quad * 4 + reg;
#pragma unroll
      for (int j = 0; j < 4; ++j) {
        int c = c0 + wc * 64 + j * 16 + col16;
        atomicAdd(&Tb[(size_t)r * 256 + c], acc[i][j][reg]);
      }
    }
  }
}

// ---------- fold projections into region space (fp32) ----------
// Tt layout: (B, 512, 256) = [r_global][c]
__global__ __launch_bounds__(256) void fold_qkv(
    const float* __restrict__ Tt1, const float* __restrict__ Tt2,
    const float* __restrict__ S1, const float* __restrict__ S2,
    const float* __restrict__ Wq, const float* __restrict__ bq,
    const float* __restrict__ Wkv, const float* __restrict__ bkv,
    float* __restrict__ qr, float* __restrict__ kr, float* __restrict__ vr) {
  int h = blockIdx.x, b = blockIdx.y;
  int t = threadIdx.x;
  int r = t & 63, d0 = (t >> 6) * 8;
  const float* T1b = Tt1 + ((size_t)b * 512 + h * 64 + r) * 256;
  const float* T2b = Tt2 + ((size_t)b * 512 + h * 64 + r) * 256;
  float aq[8] = {}, ak[8] = {}, av[8] = {};
  for (int c = 0; c < 256; ++c) {
    float t1 = T1b[c];
    float t2 = T2b[c];
#pragma unroll
    for (int i = 0; i < 8; ++i) {
      int d = d0 + i;
      aq[i] += Wq[(size_t)(h * 32 + d) * 256 + c] * t1;
      ak[i] += Wkv[(size_t)(h * 64 + d) * 256 + c] * t2;
      av[i] += Wkv[(size_t)(h * 64 + 32 + d) * 256 + c] * t2;
    }
  }
  float s1 = S1[(size_t)b * 512 + h * 64 + r];
  float s2 = S2[(size_t)b * 512 + h * 64 + r];
  size_t off = ((size_t)b * HEADS + h) * 32 * 64;
#pragma unroll
  for (int i = 0; i < 8; ++i) {
    int d = d0 + i;
    qr[off + (size_t)d * 64 + r] = aq[i] + bq[h * 32 + d] * s1;
    kr[off + (size_t)d * 64 + r] = ak[i] + bkv[h * 64 + d] * s2;
    vr[off + (size_t)d * 64 + r] = av[i] + bkv[h * 64 + 32 + d] * s2;
  }
}

// ---------- region attention + Wout fold (fp32). One block per (b,h). ----------
__global__ __launch_bounds__(256) void region_attn(
    const float* __restrict__ qr, const float* __restrict__ kr,
    const float* __restrict__ vr, const float* __restrict__ Wout,
    float* __restrict__ M) {
  int h = blockIdx.x, b = blockIdx.y;
  __shared__ float qrs[32 * 64];
  __shared__ float krs[32 * 64];
  __shared__ float vrs[32 * 64];
  __shared__ float sc[64][65];
  __shared__ float vals[32][64];
  size_t off = ((size_t)b * HEADS + h) * 32 * 64;
  int t = threadIdx.x;
  for (int i = t; i < 2048; i += 256) {
    qrs[i] = qr[off + i];
    krs[i] = kr[off + i];
    vrs[i] = vr[off + i];
  }
  __syncthreads();
  for (int idx = t; idx < 4096; idx += 256) {
    int qq = idx >> 6, kk = idx & 63;
    float s = 0.f;
#pragma unroll
    for (int d = 0; d < 32; ++d) s += qrs[d * 64 + qq] * krs[d * 64 + kk];
    sc[qq][kk] = s * 0.17677669529663687f;
  }
  __syncthreads();
  if (t < 64) {
    float m = -1e30f;
    for (int k = 0; k < 64; ++k) m = fmaxf(m, sc[t][k]);
    float s = 0.f;
    for (int k = 0; k < 64; ++k) { float e = expf(sc[t][k] - m); sc[t][k] = e; s += e; }
    float inv = 1.f / s;
    for (int k = 0; k < 64; ++k) sc[t][k] *= inv;
  }
  __syncthreads();
  for (int idx = t; idx < 2048; idx += 256) {
    int d = idx >> 6, qq = idx & 63;
    float s = 0.f;
#pragma unroll
    for (int k = 0; k < 64; ++k) s += vrs[d * 64 + k] * sc[qq][k];
    vals[d][qq] = s;
  }
  __syncthreads();
  int o = t;
  float w[32];
#pragma unroll
  for (int d = 0; d < 32; ++d) w[d] = Wout[(size_t)o * 256 + h * 32 + d];
  float* Mp = M + ((size_t)b * 256 + o) * 512 + h * 64;
  for (int r = 0; r < 64; ++r) {
    float s = 0.f;
#pragma unroll
    for (int d = 0; d < 32; ++d) s += w[d] * vals[d][r];
    Mp[r] = s;
  }
}

// ---------- final MFMA: out[b,o,n] = tgt + alpha*(bout[o] + sum_j M[b,o,j]*Rqt[b,n,j]) ----------
// M_bf: (B,256,512). Rqt: (B,N,512) bf16. K=512.
__global__ __launch_bounds__(256) void mfma_final(
    const bf16* __restrict__ Mb_, const float* __restrict__ bout,
    const bf16* __restrict__ Rqt, const float* __restrict__ tgt,
    const float* __restrict__ alpha_p, float* __restrict__ Y, int N) {
  const int K = 512;
  __shared__ bf16 As[128 * 32];
  __shared__ bf16 Bs[128 * 32];
  int b = blockIdx.z;
  int n0 = blockIdx.x * 128, o0 = blockIdx.y * 128;
  const bf16* Ab = Mb_ + (size_t)b * 256 * K;
  const bf16* Bb = Rqt + (size_t)b * N * K;
  int t = threadIdx.x;
  int lane = t & 63, wave = t >> 6;
  int wr = wave >> 1, wc = wave & 1;
  f32x4 acc[4][4] = {};
  for (int k0 = 0; k0 < K; k0 += 32) {
#pragma unroll
    for (int p = 0; p < 2; ++p) {
      int u = p * 256 + t;
      int ub = p * 256 + (t & 192);
      load_lds16(&Ab[(size_t)(o0 + (u >> 2)) * K + k0 + (u & 3) * 8], &As[ub * 8]);
      load_lds16(&Bb[(size_t)(n0 + (u >> 2)) * K + k0 + (u & 3) * 8], &Bs[ub * 8]);
    }
    __syncthreads();
    bf16x8 bfrag[4];
#pragma unroll
    for (int j = 0; j < 4; ++j)
      bfrag[j] = *(const bf16x8*)&Bs[(wc * 64 + j * 16 + (lane & 15)) * 32 + (lane >> 4) * 8];
#pragma unroll
    for (int i = 0; i < 4; ++i) {
      bf16x8 a = *(const bf16x8*)&As[(wr * 64 + i * 16 + (lane & 15)) * 32 + (lane >> 4) * 8];
#pragma unroll
      for (int j = 0; j < 4; ++j)
        acc[i][j] = __builtin_amdgcn_mfma_f32_16x16x32_bf16(a, bfrag[j], acc[i][j], 0, 0, 0);
    }
    __syncthreads();
  }
  float alpha = alpha_p[0];
  const float* Tb = tgt + (size_t)b * 256 * N;
  float* Yb = Y + (size_t)b * 256 * N;
  int quad = lane >> 4, col16 = lane & 15;
#pragma unroll
  for (int i = 0; i < 4; ++i) {
#pragma unroll
    for (int reg = 0; reg < 4; ++reg) {
      int row = o0 + wr * 64 + i * 16 + quad * 4 + reg;
      float bv = bout[row];
#pragma unroll
      for (int j = 0; j < 4; ++j) {
        int col = n0 + wc * 64 + j * 16 + col16;
        size_t idx = (size_t)row * N + col;
        Yb[idx] = Tb[idx] + alpha * (acc[i][j][reg] + bv);
      }
    }
  }
}

extern "C" void kernel_launch(void* const* d_in, const int* in_sizes, int n_in,
                              void* d_out, int out_size, void* d_ws, size_t ws_size,
                              hipStream_t stream) {
  const float* src  = (const float*)d_in[0];
  const float* tgt  = (const float*)d_in[1];
  const float* Wq   = (const float*)d_in[2];
  const float* bq   = (const float*)d_in[3];
  const float* Wkv  = (const float*)d_in[4];
  const float* bkv  = (const float*)d_in[5];
  const float* Wrq  = (const float*)d_in[6];
  const float* brq  = (const float*)d_in[7];
  const float* Wrk  = (const float*)d_in[8];
  const float* brk  = (const float*)d_in[9];
  const float* Wout = (const float*)d_in[10];
  const float* bout = (const float*)d_in[11];
  const float* alpha = (const float*)d_in[12];
  float* out = (float*)d_out;

  const int N = NPIX;
  char* p = (char*)d_ws;
  bf16* xt    = (bf16*)p;  p += (size_t)BATCH * N * 256 * 2;        // 37.7 MB
  bf16* buf1  = (bf16*)p;  p += (size_t)BATCH * 512 * N * 2;        // 75.5 MB
  bf16* buf2  = (bf16*)p;  p += (size_t)BATCH * 512 * N * 2;        // 75.5 MB
  float* Tt1  = (float*)p; p += (size_t)BATCH * 512 * 256 * 4;      // 4 MB
  float* Tt2  = (float*)p; p += (size_t)BATCH * 512 * 256 * 4;      // 4 MB
  float* S1   = (float*)p; p += (size_t)BATCH * 512 * 4;
  float* S2   = (float*)p; p += (size_t)BATCH * 512 * 4;
  float* qr   = (float*)p; p += (size_t)BATCH * HEADS * 32 * 64 * 4;
  float* kr   = (float*)p; p += (size_t)BATCH * HEADS * 32 * 64 * 4;
  float* vr   = (float*)p; p += (size_t)BATCH * HEADS * 32 * 64 * 4;
  float* Mf   = (float*)p; p += (size_t)BATCH * 256 * 512 * 4;      // 4 MB
  bf16* Wrk_b = (bf16*)p;  p += (size_t)512 * 256 * 2;
  bf16* Wrq_b = (bf16*)p;  p += (size_t)512 * 256 * 2;
  bf16* M_b   = (bf16*)p;  p += (size_t)BATCH * 256 * 512 * 2;

  dim3 blk(256);
  // weights -> bf16
  cvt_f2b<<<dim3(512 * 256 / 256), blk, 0, stream>>>(Wrk, Wrk_b, 512 * 256);
  cvt_f2b<<<dim3(512 * 256 / 256), blk, 0, stream>>>(Wrq, Wrq_b, 512 * 256);

  // ---- Rk phase ----
  transpose_cvt<<<dim3(N / 32, 8, BATCH), blk, 0, stream>>>(src, xt, 256, N);
  mfma_conv<<<dim3(N / 128, 4, BATCH), blk, 0, stream>>>(Wrk_b, brk, xt, buf1, 512, N);
  softmax_bf<<<dim3(N / 256, BATCH), blk, 0, stream>>>(buf1, N);
  rowsum_bf<<<dim3(128, BATCH), blk, 0, stream>>>(buf1, S2, N);
  hipMemsetAsync(Tt2, 0, (size_t)BATCH * 512 * 256 * 4, stream);
  gemm_T_mfma<<<dim3(2, 4, BATCH * 16), blk, 0, stream>>>(buf1, src, Tt2, N);

  // ---- Rq phase ----
  transpose_cvt<<<dim3(N / 32, 8, BATCH), blk, 0, stream>>>(tgt, xt, 256, N);
  mfma_conv<<<dim3(N / 128, 4, BATCH), blk, 0, stream>>>(Wrq_b, brq, xt, buf2, 512, N);
  softmax_bf<<<dim3(N / 256, BATCH), blk, 0, stream>>>(buf2, N);
  rowsum_bf<<<dim3(128, BATCH), blk, 0, stream>>>(buf2, S1, N);
  hipMemsetAsync(Tt1, 0, (size_t)BATCH * 512 * 256 * 4, stream);
  gemm_T_mfma<<<dim3(2, 4, BATCH * 16), blk, 0, stream>>>(buf2, tgt, Tt1, N);
  transpose_bf<<<dim3(N / 32, 16, BATCH), blk, 0, stream>>>(buf2, buf1, 512, N);  // buf1 = Rq^T (N,512)

  // ---- fold, attention, back-projection ----
  fold_qkv<<<dim3(HEADS, BATCH), blk, 0, stream>>>(Tt1, Tt2, S1, S2, Wq, bq, Wkv, bkv, qr, kr, vr);
  region_attn<<<dim3(HEADS, BATCH), blk, 0, stream>>>(qr, kr, vr, Wout, Mf);
  cvt_f2b<<<dim3(BATCH * 256 * 512 / 256), blk, 0, stream>>>(Mf, M_b, BATCH * 256 * 512);
  mfma_final<<<dim3(N / 128, 2, BATCH), blk, 0, stream>>>(M_b, bout, buf1, tgt, alpha, out, N);
}

// Round 4
// 872.740 us; speedup vs baseline: 4.3775x; 1.7976x over previous
//
#include <hip/hip_runtime.h>
#include <math.h>

#define NPIX 9216   // 96*96
#define BATCH 8
#define HEADS 8

typedef __bf16 bf16;
typedef __bf16 bf16x8 __attribute__((ext_vector_type(8)));
typedef __bf16 bf16x4 __attribute__((ext_vector_type(4)));
typedef __bf16 bf16x2 __attribute__((ext_vector_type(2)));
typedef float f32x4 __attribute__((ext_vector_type(4)));

__device__ __forceinline__ void load_lds16(const bf16* g, bf16* l) {
  __builtin_amdgcn_global_load_lds(
      (const __attribute__((address_space(1))) void*)g,
      (__attribute__((address_space(3))) void*)l, 16, 0, 0);
}

// ---------- fp32 -> bf16 elementwise ----------
__global__ __launch_bounds__(256) void cvt_f2b(const float* __restrict__ in,
                                               bf16* __restrict__ out, int n) {
  int i = blockIdx.x * 256 + threadIdx.x;
  if (i < n) out[i] = (bf16)in[i];
}

// ---------- transpose+cvt: (B,C,N) fp32 -> (B,N,C) bf16 ----------
__global__ __launch_bounds__(256) void transpose_cvt(
    const float* __restrict__ in, bf16* __restrict__ out, int C, int N) {
  __shared__ float tile[32][33];
  int b = blockIdx.z;
  int n0 = blockIdx.x * 32, c0 = blockIdx.y * 32;
  int tx = threadIdx.x & 31, ty = threadIdx.x >> 5;
#pragma unroll
  for (int k = 0; k < 4; ++k)
    tile[ty + k * 8][tx] = in[((size_t)b * C + c0 + ty + k * 8) * N + n0 + tx];
  __syncthreads();
#pragma unroll
  for (int k = 0; k < 4; ++k)
    out[((size_t)b * N + n0 + ty + k * 8) * C + c0 + tx] = (bf16)tile[tx][ty + k * 8];
}

// ---------- fused channel-softmax (512 ch) + rowsum + optional transpose ----------
// A: (B,512,N) bf16 in-place. S: (B,512) fp32, must be pre-zeroed (atomicAdd).
// If writeT, also writes At: (B,N,512) bf16.
__global__ __launch_bounds__(256) void softmax_fused(
    bf16* __restrict__ A, float* __restrict__ S, bf16* __restrict__ At,
    int N, int writeT) {
  __shared__ bf16 tile[512][34];
  __shared__ float redm[8][32];
  __shared__ float reds[8][32];
  int b = blockIdx.y;
  int n0 = blockIdx.x * 32;
  bf16* Ab = A + (size_t)b * 512 * N;
  int t = threadIdx.x;
  // load (512 x 32) tile, bf16x2 chunks, coalesced
#pragma unroll 8
  for (int i = 0; i < 32; ++i) {
    int idx = i * 256 + t;
    int c = idx >> 4, ch = idx & 15;
    *(bf16x2*)&tile[c][ch * 2] = *(const bf16x2*)&Ab[(size_t)c * N + n0 + ch * 2];
  }
  __syncthreads();
  int n = t & 31, oct = t >> 5;  // 8 threads per column, oct-interleaved channels
  float m = -1e30f;
#pragma unroll 8
  for (int k = 0; k < 64; ++k) m = fmaxf(m, (float)tile[k * 8 + oct][n]);
  redm[oct][n] = m;
  __syncthreads();
  if (t < 32) {
    float mm = redm[0][t];
#pragma unroll
    for (int o = 1; o < 8; ++o) mm = fmaxf(mm, redm[o][t]);
    redm[0][t] = mm;
  }
  __syncthreads();
  float mm = redm[0][n];
  float s = 0.f;
#pragma unroll 8
  for (int k = 0; k < 64; ++k) {
    int c = k * 8 + oct;
    float e = expf((float)tile[c][n] - mm);
    s += e;
    tile[c][n] = (bf16)e;
  }
  reds[oct][n] = s;
  __syncthreads();
  if (t < 32) {
    float ss = reds[0][t];
#pragma unroll
    for (int o = 1; o < 8; ++o) ss += reds[o][t];
    reds[0][t] = ss;
  }
  __syncthreads();
  float inv = 1.f / reds[0][n];
#pragma unroll 8
  for (int k = 0; k < 64; ++k) {
    int c = k * 8 + oct;
    tile[c][n] = (bf16)((float)tile[c][n] * inv);
  }
  __syncthreads();
  // write back (512,N), coalesced
#pragma unroll 8
  for (int i = 0; i < 32; ++i) {
    int idx = i * 256 + t;
    int c = idx >> 4, ch = idx & 15;
    *(bf16x2*)&Ab[(size_t)c * N + n0 + ch * 2] = *(const bf16x2*)&tile[c][ch * 2];
  }
  // fused rowsum: 2 channels per thread, partial over this tile's 32 n
  {
    int c0 = 2 * t, c1 = 2 * t + 1;
    float s0 = 0.f, s1 = 0.f;
#pragma unroll 8
    for (int nn = 0; nn < 32; ++nn) {
      s0 += (float)tile[c0][nn];
      s1 += (float)tile[c1][nn];
    }
    atomicAdd(&S[(size_t)b * 512 + c0], s0);
    atomicAdd(&S[(size_t)b * 512 + c1], s1);
  }
  // fused transpose: At[b,n,c], 2 channels per thread per row, coalesced
  if (writeT) {
    bf16* Atb = At + (size_t)b * N * 512;
#pragma unroll 4
    for (int nn = 0; nn < 32; ++nn) {
      bf16x2 v = {tile[2 * t][nn], tile[2 * t + 1][nn]};
      *(bf16x2*)&Atb[(size_t)(n0 + nn) * 512 + 2 * t] = v;
    }
  }
}

// ---------- MFMA conv: Y[b,o,n](bf16) = bias[o] + sum_c W[o,c]*Xt[b,n,c] ----------
__global__ __launch_bounds__(256) void mfma_conv(
    const bf16* __restrict__ W, const float* __restrict__ bias,
    const bf16* __restrict__ Xt, bf16* __restrict__ Y, int O, int N) {
  const int K = 256;
  __shared__ bf16 As[128 * 32];
  __shared__ bf16 Bs[128 * 32];
  int b = blockIdx.z;
  int n0 = blockIdx.x * 128, o0 = blockIdx.y * 128;
  const bf16* Xb = Xt + (size_t)b * N * K;
  int t = threadIdx.x;
  int lane = t & 63, wave = t >> 6;
  int wr = wave >> 1, wc = wave & 1;
  f32x4 acc[4][4] = {};
  for (int k0 = 0; k0 < K; k0 += 32) {
#pragma unroll
    for (int p = 0; p < 2; ++p) {
      int u = p * 256 + t;
      int ub = p * 256 + (t & 192);
      load_lds16(&W[(size_t)(o0 + (u >> 2)) * K + k0 + (u & 3) * 8], &As[ub * 8]);
      load_lds16(&Xb[(size_t)(n0 + (u >> 2)) * K + k0 + (u & 3) * 8], &Bs[ub * 8]);
    }
    __syncthreads();
    bf16x8 bfrag[4];
#pragma unroll
    for (int j = 0; j < 4; ++j)
      bfrag[j] = *(const bf16x8*)&Bs[(wc * 64 + j * 16 + (lane & 15)) * 32 + (lane >> 4) * 8];
#pragma unroll
    for (int i = 0; i < 4; ++i) {
      bf16x8 a = *(const bf16x8*)&As[(wr * 64 + i * 16 + (lane & 15)) * 32 + (lane >> 4) * 8];
#pragma unroll
      for (int j = 0; j < 4; ++j)
        acc[i][j] = __builtin_amdgcn_mfma_f32_16x16x32_bf16(a, bfrag[j], acc[i][j], 0, 0, 0);
    }
    __syncthreads();
  }
  bf16* Yb = Y + (size_t)b * O * N;
  int quad = lane >> 4, col16 = lane & 15;
#pragma unroll
  for (int i = 0; i < 4; ++i) {
#pragma unroll
    for (int reg = 0; reg < 4; ++reg) {
      int row = o0 + wr * 64 + i * 16 + quad * 4 + reg;
      float bv = bias[row];
#pragma unroll
      for (int j = 0; j < 4; ++j) {
        int col = n0 + wc * 64 + j * 16 + col16;
        Yb[(size_t)row * N + col] = (bf16)(acc[i][j][reg] + bv);
      }
    }
  }
}

// ---------- gemm_T (MFMA, split-K): Tt[b,r,c] += sum_n Rm[b,r,n]*X[b,c,n] ----------
__global__ __launch_bounds__(256) void gemm_T_mfma(
    const bf16* __restrict__ Rm, const float* __restrict__ Xf,
    float* __restrict__ Tt, int N) {
  __shared__ bf16 As[128 * 32];
  __shared__ bf16 Bs[128 * 32];
  int z = blockIdx.z;
  int b = z >> 4, ks = z & 15;
  int klen = N / 16;
  int kbase = ks * klen;
  int c0 = blockIdx.x * 128, r0 = blockIdx.y * 128;
  const bf16* Rb = Rm + (size_t)b * 512 * N;
  const float* Xb = Xf + (size_t)b * 256 * N;
  int t = threadIdx.x;
  int lane = t & 63, wave = t >> 6;
  int wr = wave >> 1, wc = wave & 1;
  f32x4 acc[4][4] = {};
  for (int kk = kbase; kk < kbase + klen; kk += 32) {
#pragma unroll
    for (int p = 0; p < 2; ++p) {
      int u = p * 256 + t;
      int ub = p * 256 + (t & 192);
      load_lds16(&Rb[(size_t)(r0 + (u >> 2)) * N + kk + (u & 3) * 8], &As[ub * 8]);
    }
#pragma unroll
    for (int p = 0; p < 4; ++p) {
      int u = p * 256 + t;
      int row = u >> 3, c4 = u & 7;
      const float4 v = *(const float4*)&Xb[(size_t)(c0 + row) * N + kk + c4 * 4];
      bf16x4 w = {(bf16)v.x, (bf16)v.y, (bf16)v.z, (bf16)v.w};
      *(bf16x4*)&Bs[row * 32 + c4 * 4] = w;
    }
    __syncthreads();
    bf16x8 bfrag[4];
#pragma unroll
    for (int j = 0; j < 4; ++j)
      bfrag[j] = *(const bf16x8*)&Bs[(wc * 64 + j * 16 + (lane & 15)) * 32 + (lane >> 4) * 8];
#pragma unroll
    for (int i = 0; i < 4; ++i) {
      bf16x8 a = *(const bf16x8*)&As[(wr * 64 + i * 16 + (lane & 15)) * 32 + (lane >> 4) * 8];
#pragma unroll
      for (int j = 0; j < 4; ++j)
        acc[i][j] = __builtin_amdgcn_mfma_f32_16x16x32_bf16(a, bfrag[j], acc[i][j], 0, 0, 0);
    }
    __syncthreads();
  }
  int quad = lane >> 4, col16 = lane & 15;
  float* Tb = Tt + (size_t)b * 512 * 256;
#pragma unroll
  for (int i = 0; i < 4; ++i) {
#pragma unroll
    for (int reg = 0; reg < 4; ++reg) {
      int r = r0 + wr * 64 + i * 16 + quad * 4 + reg;
#pragma unroll
      for (int j = 0; j < 4; ++j) {
        int c = c0 + wc * 64 + j * 16 + col16;
        atomicAdd(&Tb[(size_t)r * 256 + c], acc[i][j][reg]);
      }
    }
  }
}

// ---------- fold projections into region space (fp32) ----------
__global__ __launch_bounds__(256) void fold_qkv(
    const float* __restrict__ Tt1, const float* __restrict__ Tt2,
    const float* __restrict__ S1, const float* __restrict__ S2,
    const float* __restrict__ Wq, const float* __restrict__ bq,
    const float* __restrict__ Wkv, const float* __restrict__ bkv,
    float* __restrict__ qr, float* __restrict__ kr, float* __restrict__ vr) {
  int h = blockIdx.x, b = blockIdx.y;
  int t = threadIdx.x;
  int r = t & 63, d0 = (t >> 6) * 8;
  const float* T1b = Tt1 + ((size_t)b * 512 + h * 64 + r) * 256;
  const float* T2b = Tt2 + ((size_t)b * 512 + h * 64 + r) * 256;
  float aq[8] = {}, ak[8] = {}, av[8] = {};
  for (int c = 0; c < 256; ++c) {
    float t1 = T1b[c];
    float t2 = T2b[c];
#pragma unroll
    for (int i = 0; i < 8; ++i) {
      int d = d0 + i;
      aq[i] += Wq[(size_t)(h * 32 + d) * 256 + c] * t1;
      ak[i] += Wkv[(size_t)(h * 64 + d) * 256 + c] * t2;
      av[i] += Wkv[(size_t)(h * 64 + 32 + d) * 256 + c] * t2;
    }
  }
  float s1 = S1[(size_t)b * 512 + h * 64 + r];
  float s2 = S2[(size_t)b * 512 + h * 64 + r];
  size_t off = ((size_t)b * HEADS + h) * 32 * 64;
#pragma unroll
  for (int i = 0; i < 8; ++i) {
    int d = d0 + i;
    qr[off + (size_t)d * 64 + r] = aq[i] + bq[h * 32 + d] * s1;
    kr[off + (size_t)d * 64 + r] = ak[i] + bkv[h * 64 + d] * s2;
    vr[off + (size_t)d * 64 + r] = av[i] + bkv[h * 64 + 32 + d] * s2;
  }
}

// ---------- region attention + Wout fold (fp32). One block per (b,h). ----------
__global__ __launch_bounds__(256) void region_attn(
    const float* __restrict__ qr, const float* __restrict__ kr,
    const float* __restrict__ vr, const float* __restrict__ Wout,
    float* __restrict__ M) {
  int h = blockIdx.x, b = blockIdx.y;
  __shared__ float qrs[32 * 64];
  __shared__ float krs[32 * 64];
  __shared__ float vrs[32 * 64];
  __shared__ float sc[64][65];
  __shared__ float vals[32][64];
  size_t off = ((size_t)b * HEADS + h) * 32 * 64;
  int t = threadIdx.x;
  for (int i = t; i < 2048; i += 256) {
    qrs[i] = qr[off + i];
    krs[i] = kr[off + i];
    vrs[i] = vr[off + i];
  }
  __syncthreads();
  for (int idx = t; idx < 4096; idx += 256) {
    int qq = idx >> 6, kk = idx & 63;
    float s = 0.f;
#pragma unroll
    for (int d = 0; d < 32; ++d) s += qrs[d * 64 + qq] * krs[d * 64 + kk];
    sc[qq][kk] = s * 0.17677669529663687f;
  }
  __syncthreads();
  if (t < 64) {
    float m = -1e30f;
    for (int k = 0; k < 64; ++k) m = fmaxf(m, sc[t][k]);
    float s = 0.f;
    for (int k = 0; k < 64; ++k) { float e = expf(sc[t][k] - m); sc[t][k] = e; s += e; }
    float inv = 1.f / s;
    for (int k = 0; k < 64; ++k) sc[t][k] *= inv;
  }
  __syncthreads();
  for (int idx = t; idx < 2048; idx += 256) {
    int d = idx >> 6, qq = idx & 63;
    float s = 0.f;
#pragma unroll
    for (int k = 0; k < 64; ++k) s += vrs[d * 64 + k] * sc[qq][k];
    vals[d][qq] = s;
  }
  __syncthreads();
  int o = t;
  float w[32];
#pragma unroll
  for (int d = 0; d < 32; ++d) w[d] = Wout[(size_t)o * 256 + h * 32 + d];
  float* Mp = M + ((size_t)b * 256 + o) * 512 + h * 64;
  for (int r = 0; r < 64; ++r) {
    float s = 0.f;
#pragma unroll
    for (int d = 0; d < 32; ++d) s += w[d] * vals[d][r];
    Mp[r] = s;
  }
}

// ---------- final MFMA: out[b,o,n] = tgt + alpha*(bout[o] + sum_j M[b,o,j]*Rqt[b,n,j]) ----------
__global__ __launch_bounds__(256) void mfma_final(
    const bf16* __restrict__ Mb_, const float* __restrict__ bout,
    const bf16* __restrict__ Rqt, const float* __restrict__ tgt,
    const float* __restrict__ alpha_p, float* __restrict__ Y, int N) {
  const int K = 512;
  __shared__ bf16 As[128 * 32];
  __shared__ bf16 Bs[128 * 32];
  int b = blockIdx.z;
  int n0 = blockIdx.x * 128, o0 = blockIdx.y * 128;
  const bf16* Ab = Mb_ + (size_t)b * 256 * K;
  const bf16* Bb = Rqt + (size_t)b * N * K;
  int t = threadIdx.x;
  int lane = t & 63, wave = t >> 6;
  int wr = wave >> 1, wc = wave & 1;
  f32x4 acc[4][4] = {};
  for (int k0 = 0; k0 < K; k0 += 32) {
#pragma unroll
    for (int p = 0; p < 2; ++p) {
      int u = p * 256 + t;
      int ub = p * 256 + (t & 192);
      load_lds16(&Ab[(size_t)(o0 + (u >> 2)) * K + k0 + (u & 3) * 8], &As[ub * 8]);
      load_lds16(&Bb[(size_t)(n0 + (u >> 2)) * K + k0 + (u & 3) * 8], &Bs[ub * 8]);
    }
    __syncthreads();
    bf16x8 bfrag[4];
#pragma unroll
    for (int j = 0; j < 4; ++j)
      bfrag[j] = *(const bf16x8*)&Bs[(wc * 64 + j * 16 + (lane & 15)) * 32 + (lane >> 4) * 8];
#pragma unroll
    for (int i = 0; i < 4; ++i) {
      bf16x8 a = *(const bf16x8*)&As[(wr * 64 + i * 16 + (lane & 15)) * 32 + (lane >> 4) * 8];
#pragma unroll
      for (int j = 0; j < 4; ++j)
        acc[i][j] = __builtin_amdgcn_mfma_f32_16x16x32_bf16(a, bfrag[j], acc[i][j], 0, 0, 0);
    }
    __syncthreads();
  }
  float alpha = alpha_p[0];
  const float* Tb = tgt + (size_t)b * 256 * N;
  float* Yb = Y + (size_t)b * 256 * N;
  int quad = lane >> 4, col16 = lane & 15;
#pragma unroll
  for (int i = 0; i < 4; ++i) {
#pragma unroll
    for (int reg = 0; reg < 4; ++reg) {
      int row = o0 + wr * 64 + i * 16 + quad * 4 + reg;
      float bv = bout[row];
#pragma unroll
      for (int j = 0; j < 4; ++j) {
        int col = n0 + wc * 64 + j * 16 + col16;
        size_t idx = (size_t)row * N + col;
        Yb[idx] = Tb[idx] + alpha * (acc[i][j][reg] + bv);
      }
    }
  }
}

extern "C" void kernel_launch(void* const* d_in, const int* in_sizes, int n_in,
                              void* d_out, int out_size, void* d_ws, size_t ws_size,
                              hipStream_t stream) {
  const float* src  = (const float*)d_in[0];
  const float* tgt  = (const float*)d_in[1];
  const float* Wq   = (const float*)d_in[2];
  const float* bq   = (const float*)d_in[3];
  const float* Wkv  = (const float*)d_in[4];
  const float* bkv  = (const float*)d_in[5];
  const float* Wrq  = (const float*)d_in[6];
  const float* brq  = (const float*)d_in[7];
  const float* Wrk  = (const float*)d_in[8];
  const float* brk  = (const float*)d_in[9];
  const float* Wout = (const float*)d_in[10];
  const float* bout = (const float*)d_in[11];
  const float* alpha = (const float*)d_in[12];
  float* out = (float*)d_out;

  const int N = NPIX;
  char* p = (char*)d_ws;
  bf16* xt    = (bf16*)p;  p += (size_t)BATCH * N * 256 * 2;        // 37.7 MB
  bf16* buf1  = (bf16*)p;  p += (size_t)BATCH * 512 * N * 2;        // 75.5 MB
  bf16* buf2  = (bf16*)p;  p += (size_t)BATCH * 512 * N * 2;        // 75.5 MB
  float* Tt1  = (float*)p; p += (size_t)BATCH * 512 * 256 * 4;      // 4 MB
  float* Tt2  = (float*)p; p += (size_t)BATCH * 512 * 256 * 4;      // 4 MB
  float* S1   = (float*)p; p += (size_t)BATCH * 512 * 4;
  float* S2   = (float*)p; p += (size_t)BATCH * 512 * 4;
  float* qr   = (float*)p; p += (size_t)BATCH * HEADS * 32 * 64 * 4;
  float* kr   = (float*)p; p += (size_t)BATCH * HEADS * 32 * 64 * 4;
  float* vr   = (float*)p; p += (size_t)BATCH * HEADS * 32 * 64 * 4;
  float* Mf   = (float*)p; p += (size_t)BATCH * 256 * 512 * 4;      // 4 MB
  bf16* Wrk_b = (bf16*)p;  p += (size_t)512 * 256 * 2;
  bf16* Wrq_b = (bf16*)p;  p += (size_t)512 * 256 * 2;
  bf16* M_b   = (bf16*)p;  p += (size_t)BATCH * 256 * 512 * 2;

  dim3 blk(256);
  // zero accumulators (S1+S2 contiguous)
  hipMemsetAsync(S1, 0, (size_t)2 * BATCH * 512 * 4, stream);
  // weights -> bf16
  cvt_f2b<<<dim3(512 * 256 / 256), blk, 0, stream>>>(Wrk, Wrk_b, 512 * 256);
  cvt_f2b<<<dim3(512 * 256 / 256), blk, 0, stream>>>(Wrq, Wrq_b, 512 * 256);

  // ---- Rk phase ----
  transpose_cvt<<<dim3(N / 32, 8, BATCH), blk, 0, stream>>>(src, xt, 256, N);
  mfma_conv<<<dim3(N / 128, 4, BATCH), blk, 0, stream>>>(Wrk_b, brk, xt, buf1, 512, N);
  softmax_fused<<<dim3(N / 32, BATCH), blk, 0, stream>>>(buf1, S2, (bf16*)nullptr, N, 0);
  hipMemsetAsync(Tt2, 0, (size_t)BATCH * 512 * 256 * 4, stream);
  gemm_T_mfma<<<dim3(2, 4, BATCH * 16), blk, 0, stream>>>(buf1, src, Tt2, N);

  // ---- Rq phase ----  (buf1 becomes Rq^T after gemm_T on Rk completes)
  transpose_cvt<<<dim3(N / 32, 8, BATCH), blk, 0, stream>>>(tgt, xt, 256, N);
  mfma_conv<<<dim3(N / 128, 4, BATCH), blk, 0, stream>>>(Wrq_b, brq, xt, buf2, 512, N);
  softmax_fused<<<dim3(N / 32, BATCH), blk, 0, stream>>>(buf2, S1, buf1, N, 1);
  hipMemsetAsync(Tt1, 0, (size_t)BATCH * 512 * 256 * 4, stream);
  gemm_T_mfma<<<dim3(2, 4, BATCH * 16), blk, 0, stream>>>(buf2, tgt, Tt1, N);

  // ---- fold, attention, back-projection ----
  fold_qkv<<<dim3(HEADS, BATCH), blk, 0, stream>>>(Tt1, Tt2, S1, S2, Wq, bq, Wkv, bkv, qr, kr, vr);
  region_attn<<<dim3(HEADS, BATCH), blk, 0, stream>>>(qr, kr, vr, Wout, Mf);
  cvt_f2b<<<dim3(BATCH * 256 * 512 / 256), blk, 0, stream>>>(Mf, M_b, BATCH * 256 * 512);
  mfma_final<<<dim3(N / 128, 2, BATCH), blk, 0, stream>>>(M_b, bout, buf1, tgt, alpha, out, N);
}

// Round 5
// 750.097 us; speedup vs baseline: 5.0933x; 1.1635x over previous
//
#include <hip/hip_runtime.h>
#include <math.h>

#define NPIX 9216   // 96*96
#define BATCH 8
#define HEADS 8

typedef __bf16 bf16;
typedef __bf16 bf16x8 __attribute__((ext_vector_type(8)));
typedef __bf16 bf16x4 __attribute__((ext_vector_type(4)));
typedef __bf16 bf16x2 __attribute__((ext_vector_type(2)));
typedef float f32x4 __attribute__((ext_vector_type(4)));

__device__ __forceinline__ void load_lds16(const bf16* g, bf16* l) {
  __builtin_amdgcn_global_load_lds(
      (const __attribute__((address_space(1))) void*)g,
      (__attribute__((address_space(3))) void*)l, 16, 0, 0);
}

// ---------- fp32 -> bf16 elementwise ----------
__global__ __launch_bounds__(256) void cvt_f2b(const float* __restrict__ in,
                                               bf16* __restrict__ out, int n) {
  int i = blockIdx.x * 256 + threadIdx.x;
  if (i < n) out[i] = (bf16)in[i];
}

// ---------- transpose+cvt: (B,C,N) fp32 -> (B,N,C) bf16 ----------
__global__ __launch_bounds__(256) void transpose_cvt(
    const float* __restrict__ in, bf16* __restrict__ out, int C, int N) {
  __shared__ float tile[32][33];
  int b = blockIdx.z;
  int n0 = blockIdx.x * 32, c0 = blockIdx.y * 32;
  int tx = threadIdx.x & 31, ty = threadIdx.x >> 5;
#pragma unroll
  for (int k = 0; k < 4; ++k)
    tile[ty + k * 8][tx] = in[((size_t)b * C + c0 + ty + k * 8) * N + n0 + tx];
  __syncthreads();
#pragma unroll
  for (int k = 0; k < 4; ++k)
    out[((size_t)b * N + n0 + ty + k * 8) * C + c0 + tx] = (bf16)tile[tx][ty + k * 8];
}

// ---------- fused channel-softmax (512 ch) + rowsum + optional transpose ----------
__global__ __launch_bounds__(256) void softmax_fused(
    bf16* __restrict__ A, float* __restrict__ S, bf16* __restrict__ At,
    int N, int writeT) {
  __shared__ bf16 tile[512][34];
  __shared__ float redm[8][32];
  __shared__ float reds[8][32];
  int b = blockIdx.y;
  int n0 = blockIdx.x * 32;
  bf16* Ab = A + (size_t)b * 512 * N;
  int t = threadIdx.x;
#pragma unroll 8
  for (int i = 0; i < 32; ++i) {
    int idx = i * 256 + t;
    int c = idx >> 4, ch = idx & 15;
    *(bf16x2*)&tile[c][ch * 2] = *(const bf16x2*)&Ab[(size_t)c * N + n0 + ch * 2];
  }
  __syncthreads();
  int n = t & 31, oct = t >> 5;
  float m = -1e30f;
#pragma unroll 8
  for (int k = 0; k < 64; ++k) m = fmaxf(m, (float)tile[k * 8 + oct][n]);
  redm[oct][n] = m;
  __syncthreads();
  if (t < 32) {
    float mm = redm[0][t];
#pragma unroll
    for (int o = 1; o < 8; ++o) mm = fmaxf(mm, redm[o][t]);
    redm[0][t] = mm;
  }
  __syncthreads();
  float mm = redm[0][n];
  float s = 0.f;
#pragma unroll 8
  for (int k = 0; k < 64; ++k) {
    int c = k * 8 + oct;
    float e = expf((float)tile[c][n] - mm);
    s += e;
    tile[c][n] = (bf16)e;
  }
  reds[oct][n] = s;
  __syncthreads();
  if (t < 32) {
    float ss = reds[0][t];
#pragma unroll
    for (int o = 1; o < 8; ++o) ss += reds[o][t];
    reds[0][t] = ss;
  }
  __syncthreads();
  float inv = 1.f / reds[0][n];
#pragma unroll 8
  for (int k = 0; k < 64; ++k) {
    int c = k * 8 + oct;
    tile[c][n] = (bf16)((float)tile[c][n] * inv);
  }
  __syncthreads();
#pragma unroll 8
  for (int i = 0; i < 32; ++i) {
    int idx = i * 256 + t;
    int c = idx >> 4, ch = idx & 15;
    *(bf16x2*)&Ab[(size_t)c * N + n0 + ch * 2] = *(const bf16x2*)&tile[c][ch * 2];
  }
  {
    int c0 = 2 * t, c1 = 2 * t + 1;
    float s0 = 0.f, s1 = 0.f;
#pragma unroll 8
    for (int nn = 0; nn < 32; ++nn) {
      s0 += (float)tile[c0][nn];
      s1 += (float)tile[c1][nn];
    }
    atomicAdd(&S[(size_t)b * 512 + c0], s0);
    atomicAdd(&S[(size_t)b * 512 + c1], s1);
  }
  if (writeT) {
    bf16* Atb = At + (size_t)b * N * 512;
#pragma unroll 4
    for (int nn = 0; nn < 32; ++nn) {
      bf16x2 v = {tile[2 * t][nn], tile[2 * t + 1][nn]};
      *(bf16x2*)&Atb[(size_t)(n0 + nn) * 512 + 2 * t] = v;
    }
  }
}

// ---------- MFMA conv: Y[b,o,n](bf16) = bias[o] + sum_c W[o,c]*Xt[b,n,c] ----------
__global__ __launch_bounds__(256) void mfma_conv(
    const bf16* __restrict__ W, const float* __restrict__ bias,
    const bf16* __restrict__ Xt, bf16* __restrict__ Y, int O, int N) {
  const int K = 256;
  __shared__ bf16 As[128 * 32];
  __shared__ bf16 Bs[128 * 32];
  int b = blockIdx.z;
  int n0 = blockIdx.x * 128, o0 = blockIdx.y * 128;
  const bf16* Xb = Xt + (size_t)b * N * K;
  int t = threadIdx.x;
  int lane = t & 63, wave = t >> 6;
  int wr = wave >> 1, wc = wave & 1;
  f32x4 acc[4][4] = {};
  for (int k0 = 0; k0 < K; k0 += 32) {
#pragma unroll
    for (int p = 0; p < 2; ++p) {
      int u = p * 256 + t;
      int ub = p * 256 + (t & 192);
      load_lds16(&W[(size_t)(o0 + (u >> 2)) * K + k0 + (u & 3) * 8], &As[ub * 8]);
      load_lds16(&Xb[(size_t)(n0 + (u >> 2)) * K + k0 + (u & 3) * 8], &Bs[ub * 8]);
    }
    __syncthreads();
    bf16x8 bfrag[4];
#pragma unroll
    for (int j = 0; j < 4; ++j)
      bfrag[j] = *(const bf16x8*)&Bs[(wc * 64 + j * 16 + (lane & 15)) * 32 + (lane >> 4) * 8];
#pragma unroll
    for (int i = 0; i < 4; ++i) {
      bf16x8 a = *(const bf16x8*)&As[(wr * 64 + i * 16 + (lane & 15)) * 32 + (lane >> 4) * 8];
#pragma unroll
      for (int j = 0; j < 4; ++j)
        acc[i][j] = __builtin_amdgcn_mfma_f32_16x16x32_bf16(a, bfrag[j], acc[i][j], 0, 0, 0);
    }
    __syncthreads();
  }
  bf16* Yb = Y + (size_t)b * O * N;
  int quad = lane >> 4, col16 = lane & 15;
#pragma unroll
  for (int i = 0; i < 4; ++i) {
#pragma unroll
    for (int reg = 0; reg < 4; ++reg) {
      int row = o0 + wr * 64 + i * 16 + quad * 4 + reg;
      float bv = bias[row];
#pragma unroll
      for (int j = 0; j < 4; ++j) {
        int col = n0 + wc * 64 + j * 16 + col16;
        Yb[(size_t)row * N + col] = (bf16)(acc[i][j][reg] + bv);
      }
    }
  }
}

// ---------- gemm_T (MFMA, split-K): Tt[b,r,c] += sum_n Rm[b,r,n]*X[b,c,n] ----------
__global__ __launch_bounds__(256) void gemm_T_mfma(
    const bf16* __restrict__ Rm, const float* __restrict__ Xf,
    float* __restrict__ Tt, int N) {
  __shared__ bf16 As[128 * 32];
  __shared__ bf16 Bs[128 * 32];
  int z = blockIdx.z;
  int b = z >> 4, ks = z & 15;
  int klen = N / 16;
  int kbase = ks * klen;
  int c0 = blockIdx.x * 128, r0 = blockIdx.y * 128;
  const bf16* Rb = Rm + (size_t)b * 512 * N;
  const float* Xb = Xf + (size_t)b * 256 * N;
  int t = threadIdx.x;
  int lane = t & 63, wave = t >> 6;
  int wr = wave >> 1, wc = wave & 1;
  f32x4 acc[4][4] = {};
  for (int kk = kbase; kk < kbase + klen; kk += 32) {
#pragma unroll
    for (int p = 0; p < 2; ++p) {
      int u = p * 256 + t;
      int ub = p * 256 + (t & 192);
      load_lds16(&Rb[(size_t)(r0 + (u >> 2)) * N + kk + (u & 3) * 8], &As[ub * 8]);
    }
#pragma unroll
    for (int p = 0; p < 4; ++p) {
      int u = p * 256 + t;
      int row = u >> 3, c4 = u & 7;
      const float4 v = *(const float4*)&Xb[(size_t)(c0 + row) * N + kk + c4 * 4];
      bf16x4 w = {(bf16)v.x, (bf16)v.y, (bf16)v.z, (bf16)v.w};
      *(bf16x4*)&Bs[row * 32 + c4 * 4] = w;
    }
    __syncthreads();
    bf16x8 bfrag[4];
#pragma unroll
    for (int j = 0; j < 4; ++j)
      bfrag[j] = *(const bf16x8*)&Bs[(wc * 64 + j * 16 + (lane & 15)) * 32 + (lane >> 4) * 8];
#pragma unroll
    for (int i = 0; i < 4; ++i) {
      bf16x8 a = *(const bf16x8*)&As[(wr * 64 + i * 16 + (lane & 15)) * 32 + (lane >> 4) * 8];
#pragma unroll
      for (int j = 0; j < 4; ++j)
        acc[i][j] = __builtin_amdgcn_mfma_f32_16x16x32_bf16(a, bfrag[j], acc[i][j], 0, 0, 0);
    }
    __syncthreads();
  }
  int quad = lane >> 4, col16 = lane & 15;
  float* Tb = Tt + (size_t)b * 512 * 256;
#pragma unroll
  for (int i = 0; i < 4; ++i) {
#pragma unroll
    for (int reg = 0; reg < 4; ++reg) {
      int r = r0 + wr * 64 + i * 16 + quad * 4 + reg;
#pragma unroll
      for (int j = 0; j < 4; ++j) {
        int c = c0 + wc * 64 + j * 16 + col16;
        atomicAdd(&Tb[(size_t)r * 256 + c], acc[i][j][reg]);
      }
    }
  }
}

// ---------- fold projections into region space (fp32, LDS-staged, c-split) ----------
// grid (HEADS, BATCH, 4). qr/kr/vr pre-zeroed; atomicAdd accumulate.
__global__ __launch_bounds__(256) void fold_qkv(
    const float* __restrict__ Tt1, const float* __restrict__ Tt2,
    const float* __restrict__ S1, const float* __restrict__ S2,
    const float* __restrict__ Wq, const float* __restrict__ bq,
    const float* __restrict__ Wkv, const float* __restrict__ bkv,
    float* __restrict__ qr, float* __restrict__ kr, float* __restrict__ vr) {
  __shared__ float T1s[64][65];
  __shared__ float T2s[64][65];
  __shared__ float Wqs[32][65];
  __shared__ float Wks[64][65];
  int h = blockIdx.x, b = blockIdx.y;
  int c0 = blockIdx.z * 64;
  int t = threadIdx.x;
  // stage tiles (coalesced rows of 64 floats)
  for (int i = t; i < 64 * 64; i += 256) {
    int row = i >> 6, col = i & 63;
    T1s[row][col] = Tt1[((size_t)b * 512 + h * 64 + row) * 256 + c0 + col];
    T2s[row][col] = Tt2[((size_t)b * 512 + h * 64 + row) * 256 + c0 + col];
    Wks[row][col] = Wkv[(size_t)(h * 64 + row) * 256 + c0 + col];
  }
  for (int i = t; i < 32 * 64; i += 256) {
    int row = i >> 6, col = i & 63;
    Wqs[row][col] = Wq[(size_t)(h * 32 + row) * 256 + c0 + col];
  }
  __syncthreads();
  int r = t & 63, d0 = (t >> 6) * 8;
  float aq[8] = {}, ak[8] = {}, av[8] = {};
#pragma unroll 8
  for (int c = 0; c < 64; ++c) {
    float t1 = T1s[r][c];
    float t2 = T2s[r][c];
#pragma unroll
    for (int i = 0; i < 8; ++i) {
      int d = d0 + i;
      aq[i] += Wqs[d][c] * t1;
      ak[i] += Wks[d][c] * t2;
      av[i] += Wks[32 + d][c] * t2;
    }
  }
  if (blockIdx.z == 0) {
    float s1 = S1[(size_t)b * 512 + h * 64 + r];
    float s2 = S2[(size_t)b * 512 + h * 64 + r];
#pragma unroll
    for (int i = 0; i < 8; ++i) {
      int d = d0 + i;
      aq[i] += bq[h * 32 + d] * s1;
      ak[i] += bkv[h * 64 + d] * s2;
      av[i] += bkv[h * 64 + 32 + d] * s2;
    }
  }
  size_t off = ((size_t)b * HEADS + h) * 32 * 64;
#pragma unroll
  for (int i = 0; i < 8; ++i) {
    int d = d0 + i;
    atomicAdd(&qr[off + (size_t)d * 64 + r], aq[i]);
    atomicAdd(&kr[off + (size_t)d * 64 + r], ak[i]);
    atomicAdd(&vr[off + (size_t)d * 64 + r], av[i]);
  }
}

// ---------- region attention + Wout fold (fp32). One block per (b,h). ----------
__global__ __launch_bounds__(256) void region_attn(
    const float* __restrict__ qr, const float* __restrict__ kr,
    const float* __restrict__ vr, const float* __restrict__ Wout,
    float* __restrict__ M) {
  int h = blockIdx.x, b = blockIdx.y;
  __shared__ float qrs[32 * 64];
  __shared__ float krs[32 * 64];
  __shared__ float vrs[32 * 64];
  __shared__ float sc[64][65];
  __shared__ float vals[32][64];
  size_t off = ((size_t)b * HEADS + h) * 32 * 64;
  int t = threadIdx.x;
  for (int i = t; i < 2048; i += 256) {
    qrs[i] = qr[off + i];
    krs[i] = kr[off + i];
    vrs[i] = vr[off + i];
  }
  __syncthreads();
  for (int idx = t; idx < 4096; idx += 256) {
    int qq = idx >> 6, kk = idx & 63;
    float s = 0.f;
#pragma unroll
    for (int d = 0; d < 32; ++d) s += qrs[d * 64 + qq] * krs[d * 64 + kk];
    sc[qq][kk] = s * 0.17677669529663687f;
  }
  __syncthreads();
  if (t < 64) {
    float m = -1e30f;
    for (int k = 0; k < 64; ++k) m = fmaxf(m, sc[t][k]);
    float s = 0.f;
    for (int k = 0; k < 64; ++k) { float e = expf(sc[t][k] - m); sc[t][k] = e; s += e; }
    float inv = 1.f / s;
    for (int k = 0; k < 64; ++k) sc[t][k] *= inv;
  }
  __syncthreads();
  for (int idx = t; idx < 2048; idx += 256) {
    int d = idx >> 6, qq = idx & 63;
    float s = 0.f;
#pragma unroll
    for (int k = 0; k < 64; ++k) s += vrs[d * 64 + k] * sc[qq][k];
    vals[d][qq] = s;
  }
  __syncthreads();
  int o = t;
  float w[32];
#pragma unroll
  for (int d = 0; d < 32; ++d) w[d] = Wout[(size_t)o * 256 + h * 32 + d];
  float* Mp = M + ((size_t)b * 256 + o) * 512 + h * 64;
  for (int r = 0; r < 64; ++r) {
    float s = 0.f;
#pragma unroll
    for (int d = 0; d < 32; ++d) s += w[d] * vals[d][r];
    Mp[r] = s;
  }
}

// ---------- final MFMA: out[b,o,n] = tgt + alpha*(bout[o] + sum_j M[b,o,j]*Rqt[b,n,j]) ----------
__global__ __launch_bounds__(256) void mfma_final(
    const bf16* __restrict__ Mb_, const float* __restrict__ bout,
    const bf16* __restrict__ Rqt, const float* __restrict__ tgt,
    const float* __restrict__ alpha_p, float* __restrict__ Y, int N) {
  const int K = 512;
  __shared__ bf16 As[128 * 32];
  __shared__ bf16 Bs[128 * 32];
  int b = blockIdx.z;
  int n0 = blockIdx.x * 128, o0 = blockIdx.y * 128;
  const bf16* Ab = Mb_ + (size_t)b * 256 * K;
  const bf16* Bb = Rqt + (size_t)b * N * K;
  int t = threadIdx.x;
  int lane = t & 63, wave = t >> 6;
  int wr = wave >> 1, wc = wave & 1;
  f32x4 acc[4][4] = {};
  for (int k0 = 0; k0 < K; k0 += 32) {
#pragma unroll
    for (int p = 0; p < 2; ++p) {
      int u = p * 256 + t;
      int ub = p * 256 + (t & 192);
      load_lds16(&Ab[(size_t)(o0 + (u >> 2)) * K + k0 + (u & 3) * 8], &As[ub * 8]);
      load_lds16(&Bb[(size_t)(n0 + (u >> 2)) * K + k0 + (u & 3) * 8], &Bs[ub * 8]);
    }
    __syncthreads();
    bf16x8 bfrag[4];
#pragma unroll
    for (int j = 0; j < 4; ++j)
      bfrag[j] = *(const bf16x8*)&Bs[(wc * 64 + j * 16 + (lane & 15)) * 32 + (lane >> 4) * 8];
#pragma unroll
    for (int i = 0; i < 4; ++i) {
      bf16x8 a = *(const bf16x8*)&As[(wr * 64 + i * 16 + (lane & 15)) * 32 + (lane >> 4) * 8];
#pragma unroll
      for (int j = 0; j < 4; ++j)
        acc[i][j] = __builtin_amdgcn_mfma_f32_16x16x32_bf16(a, bfrag[j], acc[i][j], 0, 0, 0);
    }
    __syncthreads();
  }
  float alpha = alpha_p[0];
  const float* Tb = tgt + (size_t)b * 256 * N;
  float* Yb = Y + (size_t)b * 256 * N;
  int quad = lane >> 4, col16 = lane & 15;
#pragma unroll
  for (int i = 0; i < 4; ++i) {
#pragma unroll
    for (int reg = 0; reg < 4; ++reg) {
      int row = o0 + wr * 64 + i * 16 + quad * 4 + reg;
      float bv = bout[row];
#pragma unroll
      for (int j = 0; j < 4; ++j) {
        int col = n0 + wc * 64 + j * 16 + col16;
        size_t idx = (size_t)row * N + col;
        Yb[idx] = Tb[idx] + alpha * (acc[i][j][reg] + bv);
      }
    }
  }
}

extern "C" void kernel_launch(void* const* d_in, const int* in_sizes, int n_in,
                              void* d_out, int out_size, void* d_ws, size_t ws_size,
                              hipStream_t stream) {
  const float* src  = (const float*)d_in[0];
  const float* tgt  = (const float*)d_in[1];
  const float* Wq   = (const float*)d_in[2];
  const float* bq   = (const float*)d_in[3];
  const float* Wkv  = (const float*)d_in[4];
  const float* bkv  = (const float*)d_in[5];
  const float* Wrq  = (const float*)d_in[6];
  const float* brq  = (const float*)d_in[7];
  const float* Wrk  = (const float*)d_in[8];
  const float* brk  = (const float*)d_in[9];
  const float* Wout = (const float*)d_in[10];
  const float* bout = (const float*)d_in[11];
  const float* alpha = (const float*)d_in[12];
  float* out = (float*)d_out;

  const int N = NPIX;
  char* p = (char*)d_ws;
  bf16* xt    = (bf16*)p;  p += (size_t)BATCH * N * 256 * 2;        // 37.7 MB
  bf16* buf1  = (bf16*)p;  p += (size_t)BATCH * 512 * N * 2;        // 75.5 MB
  bf16* buf2  = (bf16*)p;  p += (size_t)BATCH * 512 * N * 2;        // 75.5 MB
  float* Tt1  = (float*)p; p += (size_t)BATCH * 512 * 256 * 4;      // 4 MB
  float* Tt2  = (float*)p; p += (size_t)BATCH * 512 * 256 * 4;      // 4 MB
  float* S1   = (float*)p; p += (size_t)BATCH * 512 * 4;
  float* S2   = (float*)p; p += (size_t)BATCH * 512 * 4;
  float* qr   = (float*)p; p += (size_t)BATCH * HEADS * 32 * 64 * 4;
  float* kr   = (float*)p; p += (size_t)BATCH * HEADS * 32 * 64 * 4;
  float* vr   = (float*)p; p += (size_t)BATCH * HEADS * 32 * 64 * 4;
  float* Mf   = (float*)p; p += (size_t)BATCH * 256 * 512 * 4;      // 4 MB
  bf16* Wrk_b = (bf16*)p;  p += (size_t)512 * 256 * 2;
  bf16* Wrq_b = (bf16*)p;  p += (size_t)512 * 256 * 2;
  bf16* M_b   = (bf16*)p;  p += (size_t)BATCH * 256 * 512 * 2;

  dim3 blk(256);
  // zero accumulators: S1,S2,qr,kr,vr are contiguous
  hipMemsetAsync(S1, 0,
                 ((size_t)2 * BATCH * 512 + (size_t)3 * BATCH * HEADS * 32 * 64) * 4,
                 stream);
  // weights -> bf16
  cvt_f2b<<<dim3(512 * 256 / 256), blk, 0, stream>>>(Wrk, Wrk_b, 512 * 256);
  cvt_f2b<<<dim3(512 * 256 / 256), blk, 0, stream>>>(Wrq, Wrq_b, 512 * 256);

  // ---- Rk phase ----
  transpose_cvt<<<dim3(N / 32, 8, BATCH), blk, 0, stream>>>(src, xt, 256, N);
  mfma_conv<<<dim3(N / 128, 4, BATCH), blk, 0, stream>>>(Wrk_b, brk, xt, buf1, 512, N);
  softmax_fused<<<dim3(N / 32, BATCH), blk, 0, stream>>>(buf1, S2, (bf16*)nullptr, N, 0);
  hipMemsetAsync(Tt2, 0, (size_t)BATCH * 512 * 256 * 4, stream);
  gemm_T_mfma<<<dim3(2, 4, BATCH * 16), blk, 0, stream>>>(buf1, src, Tt2, N);

  // ---- Rq phase ----
  transpose_cvt<<<dim3(N / 32, 8, BATCH), blk, 0, stream>>>(tgt, xt, 256, N);
  mfma_conv<<<dim3(N / 128, 4, BATCH), blk, 0, stream>>>(Wrq_b, brq, xt, buf2, 512, N);
  softmax_fused<<<dim3(N / 32, BATCH), blk, 0, stream>>>(buf2, S1, buf1, N, 1);
  hipMemsetAsync(Tt1, 0, (size_t)BATCH * 512 * 256 * 4, stream);
  gemm_T_mfma<<<dim3(2, 4, BATCH * 16), blk, 0, stream>>>(buf2, tgt, Tt1, N);

  // ---- fold, attention, back-projection ----
  fold_qkv<<<dim3(HEADS, BATCH, 4), blk, 0, stream>>>(Tt1, Tt2, S1, S2, Wq, bq, Wkv, bkv, qr, kr, vr);
  region_attn<<<dim3(HEADS, BATCH), blk, 0, stream>>>(qr, kr, vr, Wout, Mf);
  cvt_f2b<<<dim3(BATCH * 256 * 512 / 256), blk, 0, stream>>>(Mf, M_b, BATCH * 256 * 512);
  mfma_final<<<dim3(N / 128, 2, BATCH), blk, 0, stream>>>(M_b, bout, buf1, tgt, alpha, out, N);
}